// Round 28
// baseline (353.715 us; speedup 1.0000x reference)
//
#include <hip/hip_runtime.h>
#include <cstddef>

#define NN 3072
#define RR 16
#define NB 16
#define FILL_BLOCKS 64
#define FILL_ITERS 2304  // NN*NN*4 quads / (FILL_BLOCKS*256 threads) = 2304 exactly

typedef float f32x4 __attribute__((ext_vector_type(4)));

// Prologue: key[i] = valid ? batch[i] : -1, plus batch row boundaries
// start[b] = first row with batch >= b (batch sorted). start[NB]=NN.
__global__ void frd_prep_kernel(const int* __restrict__ cls,
                                const int* __restrict__ batch,
                                int* __restrict__ key,
                                int* __restrict__ start) {
    int t = blockIdx.x * blockDim.x + threadIdx.x;
    if (t < NN) {
        int c = cls[t];
        int b = batch[t];
        key[t] = (c != 24 && c != 25 && c != 26) ? b : -1;
        int prev = (t == 0) ? -1 : batch[t - 1];
        for (int bb = prev + 1; bb <= b; ++bb) start[bb] = t;
        if (t == NN - 1)
            for (int bb = b + 1; bb <= NB; ++bb) start[bb] = NN;
    }
}

// Phase 1: pure unconditional NT fill, 64 blocks grid-stride (proven-optimal:
// 6.3 TB/s). Zero per-store work — the only structure that sustains this rate.
// ENDS with __threadfence(): s_endpgm does not drain vmcnt, and the dispatch
// EOP fence flushes L2 only — NT stores bypass L2, so without an explicit
// vmcnt drain a retired wave's stores can land AFTER the next dispatch's
// writes to the same line (R23's post-timing divergence). The fence makes
// each wave confirm its stores before retiring -> dispatch barrier suffices.
__global__ __launch_bounds__(256)
void frd_fill_kernel(float* __restrict__ out) {
    const int t = blockIdx.x * 256 + threadIdx.x;        // [0, 16384)
    const float d0 = ((t & 3) == 0) ? 1.0f : 0.0f;
    const f32x4 r = {d0, 0.0f, 0.0f, 0.0f};
    float* p = out + (size_t)t * 4;
    const size_t step = (size_t)FILL_BLOCKS * 256 * 4;   // 256 KB in floats
#pragma unroll 8
    for (int it = 0; it < FILL_ITERS; ++it) {
        __builtin_nontemporal_store(r, reinterpret_cast<f32x4*>(p));
        p += step;
    }
    __threadfence();   // drain NT stores before wave retire (see comment above)
}

// Phase 3: overwrite true pairs only. One block per row i (exit if key
// invalid). 4 lanes per pair (lane q writes quad q) -> each written pair is
// one full 64 B line, coalesced across the wave. Sweeps row i's batch range.
// Same explicit drain before retire (validation copy must not race stores).
__global__ __launch_bounds__(256)
void frd_diag_kernel(const float* __restrict__ z1,
                     const float* __restrict__ z2,
                     const float* __restrict__ seg,
                     const int* __restrict__ key,
                     const int* __restrict__ start,
                     float* __restrict__ out) {
    const int i = blockIdx.x;
    const int ki = key[i];
    if (ki >= 0) {
        const int s0 = start[ki];
        const int s1 = start[ki + 1];
        const int q = threadIdx.x & 3;
        const int g = threadIdx.x >> 2;   // pair group [0,64)

        const float4 a = *reinterpret_cast<const float4*>(z1 + i * RR + q * 4);

        for (int j = s0 + g; j < s1; j += 64) {
            if (key[j] != ki) continue;               // fill's default stands
            const float s = seg[i * NN + j];          // 4-lane broadcast
            const float seg_eff = s + ((i == j) ? 1.0f : 0.0f);
            if (seg_eff != 0.0f) continue;            // default stands
            const float4 b = *reinterpret_cast<const float4*>(z2 + j * RR + q * 4);
            f32x4 r;
            r.x = a.x * b.x; r.y = a.y * b.y; r.z = a.z * b.z; r.w = a.w * b.w;
            float* op = out + ((size_t)i * NN + j) * RR + q * 4;
            __builtin_nontemporal_store(r, reinterpret_cast<f32x4*>(op));
        }
    }
    __threadfence();   // drain NT stores before wave retire
}

extern "C" void kernel_launch(void* const* d_in, const int* in_sizes, int n_in,
                              void* d_out, int out_size, void* d_ws, size_t ws_size,
                              hipStream_t stream) {
    const float* z1  = (const float*)d_in[0];
    const float* z2  = (const float*)d_in[1];
    const float* seg = (const float*)d_in[2];
    const int* cls   = (const int*)d_in[3];
    const int* batch = (const int*)d_in[4];
    float* out = (float*)d_out;
    int* key   = (int*)d_ws;
    int* start = key + NN;

    frd_fill_kernel<<<FILL_BLOCKS, 256, 0, stream>>>(out);
    frd_prep_kernel<<<(NN + 255) / 256, 256, 0, stream>>>(cls, batch, key, start);
    frd_diag_kernel<<<NN, 256, 0, stream>>>(z1, z2, seg, key, start, out);
}

// Round 29
// 106.062 us; speedup vs baseline: 3.3350x; 3.3350x over previous
//
#include <hip/hip_runtime.h>
#include <cstddef>

#define NN 3072
#define RR 16
#define NB 16
#define FILL_BLOCKS 64
#define FILL_ITERS 2304  // NN*NN*4 quads / (FILL_BLOCKS*256 threads) = 2304 exactly

typedef float f32x4 __attribute__((ext_vector_type(4)));

// Drain this wave's outstanding vector-memory ops (incl. NT stores) WITHOUT
// the L2 writeback/invalidate that __threadfence() adds (R28: that cache
// maintenance cost ~250 us). Once acked, same-line stores from any LATER
// dispatch arrive later at the controller FIFO -> strict ordering across
// dispatches; closes R23's replay race for ~0 cost.
__device__ __forceinline__ void drain_stores() {
    asm volatile("s_waitcnt vmcnt(0)" ::: "memory");
}

// Prologue: key[i] = valid ? batch[i] : -1, plus batch row boundaries
// start[b] = first row with batch >= b (batch sorted). start[NB]=NN.
__global__ void frd_prep_kernel(const int* __restrict__ cls,
                                const int* __restrict__ batch,
                                int* __restrict__ key,
                                int* __restrict__ start) {
    int t = blockIdx.x * blockDim.x + threadIdx.x;
    if (t < NN) {
        int c = cls[t];
        int b = batch[t];
        key[t] = (c != 24 && c != 25 && c != 26) ? b : -1;
        int prev = (t == 0) ? -1 : batch[t - 1];
        for (int bb = prev + 1; bb <= b; ++bb) start[bb] = t;
        if (t == NN - 1)
            for (int bb = b + 1; bb <= NB; ++bb) start[bb] = NN;
    }
}

// Phase 1: pure unconditional NT fill, 64 blocks grid-stride (proven optimal:
// 6.3 TB/s — zero per-store work is the ONLY structure that sustains it).
// Ends with a raw vmcnt(0) drain so every store is acked before wave retire.
__global__ __launch_bounds__(256)
void frd_fill_kernel(float* __restrict__ out) {
    const int t = blockIdx.x * 256 + threadIdx.x;        // [0, 16384)
    const float d0 = ((t & 3) == 0) ? 1.0f : 0.0f;
    const f32x4 r = {d0, 0.0f, 0.0f, 0.0f};
    float* p = out + (size_t)t * 4;
    const size_t step = (size_t)FILL_BLOCKS * 256 * 4;   // 256 KB in floats
#pragma unroll 8
    for (int it = 0; it < FILL_ITERS; ++it) {
        __builtin_nontemporal_store(r, reinterpret_cast<f32x4*>(p));
        p += step;
    }
    drain_stores();
}

// Phase 3: overwrite true pairs only. One block per row i (exit if key
// invalid). 4 lanes per pair (lane q writes quad q) -> each written pair is
// one full 64 B line, coalesced across the wave. Sweeps row i's batch range.
// Raw vmcnt(0) drain before retire (same-line ordering vs later replays).
__global__ __launch_bounds__(256)
void frd_diag_kernel(const float* __restrict__ z1,
                     const float* __restrict__ z2,
                     const float* __restrict__ seg,
                     const int* __restrict__ key,
                     const int* __restrict__ start,
                     float* __restrict__ out) {
    const int i = blockIdx.x;
    const int ki = key[i];
    if (ki >= 0) {
        const int s0 = start[ki];
        const int s1 = start[ki + 1];
        const int q = threadIdx.x & 3;
        const int g = threadIdx.x >> 2;   // pair group [0,64)

        const float4 a = *reinterpret_cast<const float4*>(z1 + i * RR + q * 4);

        for (int j = s0 + g; j < s1; j += 64) {
            if (key[j] != ki) continue;               // fill's default stands
            const float s = seg[i * NN + j];          // 4-lane broadcast
            const float seg_eff = s + ((i == j) ? 1.0f : 0.0f);
            if (seg_eff != 0.0f) continue;            // default stands
            const float4 b = *reinterpret_cast<const float4*>(z2 + j * RR + q * 4);
            f32x4 r;
            r.x = a.x * b.x; r.y = a.y * b.y; r.z = a.z * b.z; r.w = a.w * b.w;
            float* op = out + ((size_t)i * NN + j) * RR + q * 4;
            __builtin_nontemporal_store(r, reinterpret_cast<f32x4*>(op));
        }
    }
    drain_stores();
}

extern "C" void kernel_launch(void* const* d_in, const int* in_sizes, int n_in,
                              void* d_out, int out_size, void* d_ws, size_t ws_size,
                              hipStream_t stream) {
    const float* z1  = (const float*)d_in[0];
    const float* z2  = (const float*)d_in[1];
    const float* seg = (const float*)d_in[2];
    const int* cls   = (const int*)d_in[3];
    const int* batch = (const int*)d_in[4];
    float* out = (float*)d_out;
    int* key   = (int*)d_ws;
    int* start = key + NN;

    frd_fill_kernel<<<FILL_BLOCKS, 256, 0, stream>>>(out);
    frd_prep_kernel<<<(NN + 255) / 256, 256, 0, stream>>>(cls, batch, key, start);
    frd_diag_kernel<<<NN, 256, 0, stream>>>(z1, z2, seg, key, start, out);
}